// Round 6
// baseline (460.671 us; speedup 1.0000x reference)
//
#include <hip/hip_runtime.h>

typedef unsigned short u16;
typedef short short8 __attribute__((ext_vector_type(8)));
typedef float f32x4 __attribute__((ext_vector_type(4)));
typedef _Float16 f16;
typedef f16 f16x2 __attribute__((ext_vector_type(2)));
typedef f16 f16x8 __attribute__((ext_vector_type(8)));

#define B_ 8
#define T_ 1024
#define E_ 1024
#define H_ 16
#define D_ 64
#define BH_ 128

__device__ __forceinline__ float ftanh(float x){
    x = fminf(8.0f, fmaxf(-8.0f, x));
    float e2 = __expf(2.0f * x);
    return 1.0f - 2.0f * __builtin_amdgcn_rcpf(e2 + 1.0f);
}

__device__ __forceinline__ u16 f2h(float x){
    union { f16 h; u16 u; } v; v.h = (f16)x; return v.u;
}

__device__ __forceinline__ f16x8 pack8(f32x4 a, f32x4 b){
    f16x8 r;
    r[0]=(f16)a[0]; r[1]=(f16)a[1]; r[2]=(f16)a[2]; r[3]=(f16)a[3];
    r[4]=(f16)b[0]; r[5]=(f16)b[1]; r[6]=(f16)b[2]; r[7]=(f16)b[3];
    return r;
}

// Opaque register pins: keep loop-resident values in VGPRs.
#define PIN8(x) do { f32x4 _t = __builtin_bit_cast(f32x4, x); \
                     asm volatile("" : "+v"(_t));             \
                     x = __builtin_bit_cast(f16x8, _t); } while (0)
#define PIN4(x) do { asm volatile("" : "+v"(x)); } while (0)

#define MFMA16(a, b, c) __builtin_amdgcn_mfma_f32_16x16x32_f16(a, b, c, 0, 0, 0)

// ---------------------------------------------------------------------------
// Kernel 1: fused RNN (blocks 0..127) + q/v projection (blocks 128..).
// RNN REWRITE (round 6): the 64x64 matvec per step moves to the MFMA pipe.
//  - B operand of mfma_16x16x32 is uniform-column (B[k][j]=h[k]): the h
//    broadcast collapses to TWO conflict-free ds_read_b128 (16-lane groups
//    read the same 16B k-slice of hl). Was 8 reads + 32 fdot2.
//  - 8 MFMAs: 4 row-blocks x 2 k-blocks; bias pre-loaded in the C operand.
//  - output row r(l)=16(l&3)+4(l>>4)+((l>>2)&3) per lane via a static
//    15-cndmask select tree; 1 tanh; 1 ds_write_b16; 1 global u16 store.
//  All fragment layouts identical to the (passing) attn kernel below.
// Rationale: rounds 1-2 showed step cost tracks the lone wave's instruction
// count / DS serialization (~504cy at ~60 instrs), not the broadcast
// mechanism. This cuts to ~38 instrs/step.
// ---------------------------------------------------------------------------
__global__ __launch_bounds__(256, 1) void proj_rnn_kernel(
    const float* __restrict__ src, const float* __restrict__ tgt,
    const float* __restrict__ Wq,  const float* __restrict__ Wv,
    const float* __restrict__ Wih, const float* __restrict__ Whh,
    const float* __restrict__ bih, const float* __restrict__ bhh,
    u16* __restrict__ qh, u16* __restrict__ vh, u16* __restrict__ nwh)
{
    int bid = blockIdx.x;
    if (bid < BH_) {
        if (threadIdx.x >= 64) return;
        __shared__ __align__(16) u16 hl[D_];
        const int b = bid >> 4, h = bid & 15;
        const int l    = threadIdx.x;
        const int l15  = l & 15;
        const int quad = l >> 4;
        // designated output row (bijection over lanes; see header comment)
        const int rsel = 16 * (l & 3) + 4 * quad + ((l >> 2) & 3);
        const bool b0 = (l & 1), b1 = (l & 2), b2 = (l & 4), b3 = (l & 8);

        // ---- A fragments: rows 16rb+l15, k-slice quad*8 + 32kb ----
        const float* WI = Wih + (size_t)h * D_ * D_;
        const float* WH = Whh + (size_t)h * D_ * D_;
        f16x8 n00,n01,n10,n11,n20,n21,n30,n31;   // Wih only (step 1)
        f16x8 m00,m01,m10,m11,m20,m21,m30,m31;   // Wih+Whh (recurrent)
        {
            #define LOADF(rb, kb, NV, MV) do {                                    \
                const float* pI = WI + (size_t)(16*(rb) + l15) * D_ + quad*8 + 32*(kb); \
                const float* pH = WH + (size_t)(16*(rb) + l15) * D_ + quad*8 + 32*(kb); \
                f32x4 ia = *(const f32x4*)pI, ib = *(const f32x4*)(pI + 4);       \
                f32x4 ha = *(const f32x4*)pH, hb = *(const f32x4*)(pH + 4);       \
                NV = pack8(ia, ib);                                               \
                MV = pack8(ia + ha, ib + hb);                                     \
            } while (0)
            LOADF(0,0,n00,m00); LOADF(0,1,n01,m01);
            LOADF(1,0,n10,m10); LOADF(1,1,n11,m11);
            LOADF(2,0,n20,m20); LOADF(2,1,n21,m21);
            LOADF(3,0,n30,m30); LOADF(3,1,n31,m31);
            #undef LOADF
        }
        // ---- bias in the C operand: cb[rb][i] for row 16rb + 4quad + i ----
        f32x4 cb0, cb1, cb2, cb3;
        {
            const float* bi = bih + h * D_;
            const float* bh2 = bhh + h * D_;
            #pragma unroll
            for (int i = 0; i < 4; ++i) {
                cb0[i] = bi[ 0 + 4*quad + i] + bh2[ 0 + 4*quad + i];
                cb1[i] = bi[16 + 4*quad + i] + bh2[16 + 4*quad + i];
                cb2[i] = bi[32 + 4*quad + i] + bh2[32 + 4*quad + i];
                cb3[i] = bi[48 + 4*quad + i] + bh2[48 + 4*quad + i];
            }
        }
        PIN8(m00); PIN8(m01); PIN8(m10); PIN8(m11);
        PIN8(m20); PIN8(m21); PIN8(m30); PIN8(m31);
        PIN4(cb0); PIN4(cb1); PIN4(cb2); PIN4(cb3);

        hl[l] = f2h(tgt[(size_t)b * T_ * E_ + h * D_ + l]);  // k0

        u16* nwp = nwh + (size_t)bid * T_ * D_;

        // one step: read h k-slices (uniform per 16-lane group), 8 MFMA,
        // select own row, tanh, write back.
        #define RNN_STEP(A00,A01,A10,A11,A20,A21,A30,A31, trow) do {             \
            f16x8 hb0 = *(const f16x8*)(hl + quad * 8);                          \
            f16x8 hb1 = *(const f16x8*)(hl + 32 + quad * 8);                     \
            f32x4 a0 = MFMA16(A00, hb0, cb0);                                    \
            f32x4 a1 = MFMA16(A10, hb0, cb1);                                    \
            f32x4 a2 = MFMA16(A20, hb0, cb2);                                    \
            f32x4 a3 = MFMA16(A30, hb0, cb3);                                    \
            a0 = MFMA16(A01, hb1, a0);                                           \
            a1 = MFMA16(A11, hb1, a1);                                           \
            a2 = MFMA16(A21, hb1, a2);                                           \
            a3 = MFMA16(A31, hb1, a3);                                           \
            f32x4 t0 = b0 ? a1 : a0;                                             \
            f32x4 t1 = b0 ? a3 : a2;                                             \
            f32x4 z  = b1 ? t1 : t0;                                             \
            float u0 = b2 ? z[1] : z[0];                                         \
            float u1 = b2 ? z[3] : z[2];                                         \
            float yv = b3 ? u1 : u0;                                             \
            u16 hb16 = f2h(ftanh(yv));                                           \
            hl[rsel] = hb16;                                                     \
            nwp[(size_t)(trow) * D_ + rsel] = hb16;                              \
        } while (0)

        // step 1: h1 = tanh(Wih k0 + c)
        RNN_STEP(n00,n01,n10,n11,n20,n21,n30,n31, 0);

        #pragma unroll 1
        for (int t = 1; t < T_; ++t) {
            RNN_STEP(m00,m01,m10,m11,m20,m21,m30,m31, t);
        }
        #undef RNN_STEP
    } else {
        int pb   = bid - BH_;          // 0 .. 4095
        int bh   = pb >> 5;            // (b*16+h)
        int tile = pb & 31;            // 32 t-rows per block
        int b = bh >> 4, h = bh & 15;
        int e  = threadIdx.x & 63;
        int tg = threadIdx.x >> 6;
        int t0 = tile * 32 + tg * 8;

        const float* wq = Wq + (size_t)h * D_ * D_ + e;  // column e, stride 64
        const float* wv = Wv + (size_t)h * D_ * D_ + e;
        const float* s0 = src + ((size_t)b * T_ + t0) * E_ + h * D_;
        const float* g0 = tgt + ((size_t)b * T_ + t0) * E_ + h * D_;

        float aq[8] = {0,0,0,0,0,0,0,0};
        float av[8] = {0,0,0,0,0,0,0,0};
        #pragma unroll 4
        for (int d4 = 0; d4 < 16; ++d4) {
            float q0 = wq[(4*d4+0)*64], q1 = wq[(4*d4+1)*64],
                  q2 = wq[(4*d4+2)*64], q3 = wq[(4*d4+3)*64];
            float v0 = wv[(4*d4+0)*64], v1 = wv[(4*d4+1)*64],
                  v2 = wv[(4*d4+2)*64], v3 = wv[(4*d4+3)*64];
            #pragma unroll
            for (int j = 0; j < 8; ++j) {
                float4 x = *(const float4*)(s0 + (size_t)j * E_ + 4*d4);
                float4 y = *(const float4*)(g0 + (size_t)j * E_ + 4*d4);
                aq[j] += x.x*q0 + x.y*q1 + x.z*q2 + x.w*q3;
                av[j] += y.x*v0 + y.y*v1 + y.z*v2 + y.w*v3;
            }
        }
        u16* qp = qh + ((size_t)bh * T_ + t0) * D_ + e;
        #pragma unroll
        for (int j = 0; j < 8; ++j) qp[(size_t)j * D_] = f2h(aq[j] * (1.0f/256.0f));
        f16x8 vv;
        #pragma unroll
        for (int j = 0; j < 8; ++j) vv[j] = (f16)av[j];
        *(f16x8*)(vh + ((size_t)bh * D_ + e) * T_ + t0) = vv;
    }
}

// ---------------------------------------------------------------------------
// Kernel 2: flash attention (unchanged from round 5, which passed at 1.2e-4):
// 128 q-rows/block, shared K/V fragments across 2 q-groups, deferred
// denominator, rcp epilogue, fused Wo projection.
// ---------------------------------------------------------------------------
__global__ __launch_bounds__(256) void attn_kernel(
    const u16* __restrict__ qh,   // [bh][t][64] f16, pre-scaled 1/256
    const u16* __restrict__ kh,   // nw states [bh][t][64] f16
    const u16* __restrict__ vh,   // V^T [bh][d][t] f16
    const float* __restrict__ Wo, // [H][64][64] fp32
    float* __restrict__ out)      // [B][T][E] fp32
{
    __shared__ __align__(16) u16 Klds[64 * 64];        // keys; later Wo^T
    __shared__ __align__(16) u16 Vlds[64 * 64];        // V^T: row=d, col=key
    __shared__ __align__(16) u16 Plds[4][2][16 * 64];  // per-wave per-group P/O

    const int tid  = threadIdx.x;
    const int lane = tid & 63;
    const int w    = tid >> 6;
    const int l15  = lane & 15;
    const int quad = lane >> 4;
    const int sw   = lane & 7;
    const int bh   = blockIdx.y;
    const int qt   = blockIdx.x;

    const size_t base  = (size_t)bh * T_ * D_;
    const size_t vbase = (size_t)bh * D_ * T_;

    // Q fragments for both 16-row groups (rows16 index = w + 4g)
    f16x8 aq[2][2];
    #pragma unroll
    for (int g = 0; g < 2; ++g) {
        int qrow = qt * 128 + (w + 4 * g) * 16 + l15;
        const f16x8* qp = (const f16x8*)(qh + base + (size_t)qrow * 64 + quad * 8);
        aq[g][0] = qp[0];
        aq[g][1] = qp[4];
    }

    f32x4 oacc[2][4];
    float lrun[2][4];
    #pragma unroll
    for (int g = 0; g < 2; ++g)
        #pragma unroll
        for (int i = 0; i < 4; ++i) {
            oacc[g][i] = (f32x4){0.f, 0.f, 0.f, 0.f};
            lrun[g][i] = 0.f;
        }

    #pragma unroll 1
    for (int kt = 0; kt < 16; ++kt) {
        // ---- stage K rows + V^T rows, vectorized b128, swizzled ----
        #pragma unroll
        for (int i = 0; i < 2; ++i) {
            int ch = tid + 256 * i;          // 512 chunks of 8 u16
            int r = ch >> 3, cc = ch & 7;
            short8 kval = *(const short8*)(kh + base + (size_t)(kt * 64 + r) * 64 + cc * 8);
            *(short8*)&Klds[r * 64 + ((cc ^ (r & 7)) * 8)] = kval;
            short8 vval = *(const short8*)(vh + vbase + (size_t)r * T_ + kt * 64 + cc * 8);
            *(short8*)&Vlds[r * 64 + ((cc ^ (r & 7)) * 8)] = vval;
        }
        __syncthreads();

        // ---- S = Q K^T, K-fragments shared across both q-groups ----
        f32x4 sacc[2][4];
        #pragma unroll
        for (int u = 0; u < 4; ++u) {
            int row = 16 * u + l15;
            f16x8 bk0 = *(const f16x8*)&Klds[row * 64 + (((quad + 0) ^ sw) * 8)];
            f16x8 bk1 = *(const f16x8*)&Klds[row * 64 + (((quad + 4) ^ sw) * 8)];
            #pragma unroll
            for (int g = 0; g < 2; ++g) {
                f32x4 z = (f32x4){0.f, 0.f, 0.f, 0.f};
                z = MFMA16(aq[g][0], bk0, z);
                z = MFMA16(aq[g][1], bk1, z);
                sacc[g][u] = z;
            }
        }

        // ---- softmax: exp + lane-local partial sums (reduce deferred) ----
        #pragma unroll
        for (int g = 0; g < 2; ++g) {
            float pr[4][4];
            #pragma unroll
            for (int r = 0; r < 4; ++r) {
                float rs = 0.f;
                #pragma unroll
                for (int u = 0; u < 4; ++u) {
                    float pv = __expf(sacc[g][u][r]);
                    pr[u][r] = pv;
                    rs += pv;
                }
                lrun[g][r] += rs;
            }
            // P -> per-wave per-group LDS (C-layout -> A-fragment layout)
            u16* Pw = Plds[w][g];
            #pragma unroll
            for (int u = 0; u < 4; ++u) {
                int col = 16 * u + l15;
                #pragma unroll
                for (int r = 0; r < 4; ++r) {
                    int row = quad * 4 + r;
                    Pw[row * 64 + (((col >> 3) ^ (row & 7)) * 8) + (col & 7)] = f2h(pr[u][r]);
                }
            }
        }

        // ---- O += P V, V-fragments shared across both q-groups ----
        #pragma unroll
        for (int kc = 0; kc < 2; ++kc) {
            int csel = ((quad + 4 * kc) ^ sw) * 8;
            f16x8 ap0 = *(const f16x8*)&Plds[w][0][l15 * 64 + csel];
            f16x8 ap1 = *(const f16x8*)&Plds[w][1][l15 * 64 + csel];
            #pragma unroll
            for (int nt = 0; nt < 4; ++nt) {
                f16x8 bv = *(const f16x8*)&Vlds[(16 * nt + l15) * 64 + csel];
                oacc[0][nt] = MFMA16(ap0, bv, oacc[0][nt]);
                oacc[1][nt] = MFMA16(ap1, bv, oacc[1][nt]);
            }
        }
        __syncthreads();
    }

    // ---- deferred denominator: one 16-lane reduce per (g, r) ----
    float inv[2][4];
    #pragma unroll
    for (int g = 0; g < 2; ++g)
        #pragma unroll
        for (int r = 0; r < 4; ++r) {
            float s = lrun[g][r];
            #pragma unroll
            for (int off = 1; off < 16; off <<= 1)
                s += __shfl_xor(s, off, 16);
            inv[g][r] = __builtin_amdgcn_rcpf(s);
        }

    // ---- fused output projection: out_tile = (O/l) * Wo[h] ----
    const int b  = bh >> 4, hh = bh & 15;
    {
        const float* wo = Wo + (size_t)hh * D_ * D_;
        #pragma unroll
        for (int i = 0; i < 2; ++i) {
            int ch = tid + 256 * i;          // e = ch>>3, dc = ch&7
            int e = ch >> 3, dc = ch & 7;
            short8 vch;
            #pragma unroll
            for (int j = 0; j < 8; ++j)
                vch[j] = (short)f2h(wo[(size_t)(dc * 8 + j) * D_ + e]);
            *(short8*)&Klds[e * 64 + ((dc ^ (e & 7)) * 8)] = vch;
        }
    }
    #pragma unroll
    for (int g = 0; g < 2; ++g) {
        u16* Pw = Plds[w][g];
        #pragma unroll
        for (int nt = 0; nt < 4; ++nt) {
            int col = 16 * nt + l15;             // d
            #pragma unroll
            for (int r = 0; r < 4; ++r) {
                int row = quad * 4 + r;          // q
                Pw[row * 64 + (((col >> 3) ^ (row & 7)) * 8) + (col & 7)] =
                    f2h(oacc[g][nt][r] * inv[g][r]);
            }
        }
    }
    __syncthreads();    // Wo^T staging + O relayout visible

    f16x8 ao[2][2];
    #pragma unroll
    for (int g = 0; g < 2; ++g) {
        ao[g][0] = *(const f16x8*)&Plds[w][g][l15 * 64 + (((quad + 0) ^ sw) * 8)];
        ao[g][1] = *(const f16x8*)&Plds[w][g][l15 * 64 + (((quad + 4) ^ sw) * 8)];
    }
    f32x4 oo[2][4];
    #pragma unroll
    for (int g = 0; g < 2; ++g)
        #pragma unroll
        for (int nt = 0; nt < 4; ++nt)
            oo[g][nt] = (f32x4){0.f, 0.f, 0.f, 0.f};
    #pragma unroll
    for (int nt = 0; nt < 4; ++nt) {
        int erow = 16 * nt + l15;
        f16x8 b0 = *(const f16x8*)&Klds[erow * 64 + (((quad + 0) ^ (erow & 7)) * 8)];
        f16x8 b1 = *(const f16x8*)&Klds[erow * 64 + (((quad + 4) ^ (erow & 7)) * 8)];
        #pragma unroll
        for (int g = 0; g < 2; ++g) {
            oo[g][nt] = MFMA16(ao[g][0], b0, oo[g][nt]);
            oo[g][nt] = MFMA16(ao[g][1], b1, oo[g][nt]);
        }
    }
    #pragma unroll
    for (int g = 0; g < 2; ++g)
        #pragma unroll
        for (int nt = 0; nt < 4; ++nt)
            #pragma unroll
            for (int r = 0; r < 4; ++r) {
                int qg = qt * 128 + (w + 4 * g) * 16 + quad * 4 + r;
                int e  = 16 * nt + l15;
                out[((size_t)b * T_ + qg) * E_ + hh * D_ + e] = oo[g][nt][r];
            }
}

// ---------------------------------------------------------------------------
extern "C" void kernel_launch(void* const* d_in, const int* in_sizes, int n_in,
                              void* d_out, int out_size, void* d_ws, size_t ws_size,
                              hipStream_t stream)
{
    const float* src = (const float*)d_in[0];
    const float* tgt = (const float*)d_in[1];
    const float* Wq  = (const float*)d_in[2];
    const float* Wv  = (const float*)d_in[3];
    const float* Wo  = (const float*)d_in[4];
    const float* Wih = (const float*)d_in[5];
    const float* Whh = (const float*)d_in[6];
    const float* bih = (const float*)d_in[7];
    const float* bhh = (const float*)d_in[8];
    float* out = (float*)d_out;

    char* ws = (char*)d_ws;
    u16* qh  = (u16*)(ws);                             // [bh][t][d] 16 MB
    u16* vh  = (u16*)(ws + (size_t)16 * 1024 * 1024);  // V^T [bh][d][t] 16 MB
    u16* nwh = (u16*)(ws + (size_t)32 * 1024 * 1024);  // [bh][t][d] 16 MB

    (void)in_sizes; (void)n_in; (void)out_size; (void)ws_size;

    proj_rnn_kernel<<<dim3(BH_ + 4096), 256, 0, stream>>>(
        src, tgt, Wq, Wv, Wih, Whh, bih, bhh, qh, vh, nwh);
    attn_kernel<<<dim3(8, BH_), 256, 0, stream>>>(qh, nwh, vh, Wo, out);
}

// Round 7
// 392.314 us; speedup vs baseline: 1.1742x; 1.1742x over previous
//
#include <hip/hip_runtime.h>

typedef unsigned short u16;
typedef unsigned int   u32;
typedef short short8 __attribute__((ext_vector_type(8)));
typedef float f32x4 __attribute__((ext_vector_type(4)));
typedef _Float16 f16;
typedef f16 f16x2 __attribute__((ext_vector_type(2)));
typedef f16 f16x8 __attribute__((ext_vector_type(8)));

#define B_ 8
#define T_ 1024
#define E_ 1024
#define H_ 16
#define D_ 64
#define BH_ 128

__device__ __forceinline__ float ftanh(float x){
    x = fminf(8.0f, fmaxf(-8.0f, x));
    float e2 = __expf(2.0f * x);
    return 1.0f - 2.0f * __builtin_amdgcn_rcpf(e2 + 1.0f);
}

__device__ __forceinline__ u16 f2h(float x){
    union { f16 h; u16 u; } v; v.h = (f16)x; return v.u;
}

__device__ __forceinline__ float dot8(f16x8 a, f16x8 b, float acc){
#if __has_builtin(__builtin_amdgcn_fdot2)
    f16x2 a0 = {a[0],a[1]}, a1 = {a[2],a[3]}, a2 = {a[4],a[5]}, a3 = {a[6],a[7]};
    f16x2 b0 = {b[0],b[1]}, b1 = {b[2],b[3]}, b2 = {b[4],b[5]}, b3 = {b[6],b[7]};
    acc = __builtin_amdgcn_fdot2(a0, b0, acc, false);
    acc = __builtin_amdgcn_fdot2(a1, b1, acc, false);
    acc = __builtin_amdgcn_fdot2(a2, b2, acc, false);
    acc = __builtin_amdgcn_fdot2(a3, b3, acc, false);
#else
    #pragma unroll
    for (int i = 0; i < 8; ++i) acc += (float)a[i] * (float)b[i];
#endif
    return acc;
}

__device__ __forceinline__ f16x8 pack8(f32x4 a, f32x4 b){
    f16x8 r;
    r[0]=(f16)a[0]; r[1]=(f16)a[1]; r[2]=(f16)a[2]; r[3]=(f16)a[3];
    r[4]=(f16)b[0]; r[5]=(f16)b[1]; r[6]=(f16)b[2]; r[7]=(f16)b[3];
    return r;
}

// Opaque register pin: keeps recurrent weights VGPR-resident across the loop.
#define PIN8(x) do { f32x4 _t = __builtin_bit_cast(f32x4, x); \
                     asm volatile("" : "+v"(_t));             \
                     x = __builtin_bit_cast(f16x8, _t); } while (0)

#define MFMA16(a, b, c) __builtin_amdgcn_mfma_f32_16x16x32_f16(a, b, c, 0, 0, 0)

// ---------------------------------------------------------------------------
// Kernel 1: fused RNN (blocks 0..127) + q/v projection (blocks 128..).
// VERBATIM round-0 RNN (217us): best of {LDS-broadcast 217, DPP 235,
// setprio 230, MFMA-matvec 306}. ~500cy/step is this structure's floor.
// ---------------------------------------------------------------------------
__global__ __launch_bounds__(256, 1) void proj_rnn_kernel(
    const float* __restrict__ src, const float* __restrict__ tgt,
    const float* __restrict__ Wq,  const float* __restrict__ Wv,
    const float* __restrict__ Wih, const float* __restrict__ Whh,
    const float* __restrict__ bih, const float* __restrict__ bhh,
    u16* __restrict__ qh, u16* __restrict__ vh, u16* __restrict__ nwh)
{
    int bid = blockIdx.x;
    if (bid < BH_) {
        if (threadIdx.x >= 64) return;
        __shared__ __align__(16) u16 hl[D_];
        const int b = bid >> 4, h = bid & 15;
        const int e = threadIdx.x;

        const f32x4* wi4 = (const f32x4*)(Wih + ((size_t)h * D_ + e) * D_);
        const f32x4* wh4 = (const f32x4*)(Whh + ((size_t)h * D_ + e) * D_);
        float c = bih[h * D_ + e] + bhh[h * D_ + e];
        asm volatile("" : "+v"(c));

        f16x8 n0 = pack8(wi4[0],  wi4[1]),  n1 = pack8(wi4[2],  wi4[3]);
        f16x8 n2 = pack8(wi4[4],  wi4[5]),  n3 = pack8(wi4[6],  wi4[7]);
        f16x8 n4 = pack8(wi4[8],  wi4[9]),  n5 = pack8(wi4[10], wi4[11]);
        f16x8 n6 = pack8(wi4[12], wi4[13]), n7 = pack8(wi4[14], wi4[15]);
        f16x8 m0 = pack8(wi4[0]+wh4[0],   wi4[1]+wh4[1]);
        f16x8 m1 = pack8(wi4[2]+wh4[2],   wi4[3]+wh4[3]);
        f16x8 m2 = pack8(wi4[4]+wh4[4],   wi4[5]+wh4[5]);
        f16x8 m3 = pack8(wi4[6]+wh4[6],   wi4[7]+wh4[7]);
        f16x8 m4 = pack8(wi4[8]+wh4[8],   wi4[9]+wh4[9]);
        f16x8 m5 = pack8(wi4[10]+wh4[10], wi4[11]+wh4[11]);
        f16x8 m6 = pack8(wi4[12]+wh4[12], wi4[13]+wh4[13]);
        f16x8 m7 = pack8(wi4[14]+wh4[14], wi4[15]+wh4[15]);
        PIN8(m0); PIN8(m1); PIN8(m2); PIN8(m3);
        PIN8(m4); PIN8(m5); PIN8(m6); PIN8(m7);

        hl[e] = f2h(tgt[(size_t)b * T_ * E_ + h * D_ + e]);  // k0

        u16* nwp = nwh + (size_t)bid * T_ * D_;
        const f16x8* hl8 = (const f16x8*)hl;

        {
            f16x8 x0=hl8[0],x1=hl8[1],x2=hl8[2],x3=hl8[3],
                  x4=hl8[4],x5=hl8[5],x6=hl8[6],x7=hl8[7];
            float s0=dot8(n0,x0,c),   s1=dot8(n1,x1,0.f),
                  s2=dot8(n2,x2,0.f), s3=dot8(n3,x3,0.f),
                  s4=dot8(n4,x4,0.f), s5=dot8(n5,x5,0.f),
                  s6=dot8(n6,x6,0.f), s7=dot8(n7,x7,0.f);
            float hv = ftanh(((s0+s1)+(s2+s3)) + ((s4+s5)+(s6+s7)));
            u16 hb = f2h(hv);
            hl[e] = hb;
            nwp[e] = hb;
        }

        #pragma unroll 1
        for (int t = 1; t < T_; ++t) {
            f16x8 x0=hl8[0],x1=hl8[1],x2=hl8[2],x3=hl8[3],
                  x4=hl8[4],x5=hl8[5],x6=hl8[6],x7=hl8[7];
            float s0=dot8(m0,x0,c),   s1=dot8(m1,x1,0.f),
                  s2=dot8(m2,x2,0.f), s3=dot8(m3,x3,0.f),
                  s4=dot8(m4,x4,0.f), s5=dot8(m5,x5,0.f),
                  s6=dot8(m6,x6,0.f), s7=dot8(m7,x7,0.f);
            float hv = ftanh(((s0+s1)+(s2+s3)) + ((s4+s5)+(s6+s7)));
            u16 hb = f2h(hv);
            hl[e] = hb;
            nwp[(size_t)t * D_ + e] = hb;
        }
    } else {
        int pb   = bid - BH_;          // 0 .. 4095
        int bh   = pb >> 5;            // (b*16+h)
        int tile = pb & 31;            // 32 t-rows per block
        int b = bh >> 4, h = bh & 15;
        int e  = threadIdx.x & 63;
        int tg = threadIdx.x >> 6;
        int t0 = tile * 32 + tg * 8;

        const float* wq = Wq + (size_t)h * D_ * D_ + e;  // column e, stride 64
        const float* wv = Wv + (size_t)h * D_ * D_ + e;
        const float* s0 = src + ((size_t)b * T_ + t0) * E_ + h * D_;
        const float* g0 = tgt + ((size_t)b * T_ + t0) * E_ + h * D_;

        float aq[8] = {0,0,0,0,0,0,0,0};
        float av[8] = {0,0,0,0,0,0,0,0};
        #pragma unroll 4
        for (int d4 = 0; d4 < 16; ++d4) {
            float q0 = wq[(4*d4+0)*64], q1 = wq[(4*d4+1)*64],
                  q2 = wq[(4*d4+2)*64], q3 = wq[(4*d4+3)*64];
            float v0 = wv[(4*d4+0)*64], v1 = wv[(4*d4+1)*64],
                  v2 = wv[(4*d4+2)*64], v3 = wv[(4*d4+3)*64];
            #pragma unroll
            for (int j = 0; j < 8; ++j) {
                float4 x = *(const float4*)(s0 + (size_t)j * E_ + 4*d4);
                float4 y = *(const float4*)(g0 + (size_t)j * E_ + 4*d4);
                aq[j] += x.x*q0 + x.y*q1 + x.z*q2 + x.w*q3;
                av[j] += y.x*v0 + y.y*v1 + y.z*v2 + y.w*v3;
            }
        }
        u16* qp = qh + ((size_t)bh * T_ + t0) * D_ + e;
        #pragma unroll
        for (int j = 0; j < 8; ++j) qp[(size_t)j * D_] = f2h(aq[j] * (1.0f/256.0f));
        f16x8 vv;
        #pragma unroll
        for (int j = 0; j < 8; ++j) vv[j] = (f16)av[j];
        *(f16x8*)(vh + ((size_t)bh * D_ + e) * T_ + t0) = vv;
    }
}

// ---------------------------------------------------------------------------
// Kernel 2: flash attention. Round-7 change: SWAPPED QK^T (mfma(K,Q)) puts
// q on the C-layout column (=l15); the P C-layout -> PV A-fragment relayout
// becomes a pure quad-axis permutation done IN REGISTERS (2x permlane16_swap
// + 1x permlane32_swap + selects per kc per group), replacing 32 scalar
// ds_write_b16 + 4 ds_read_b128 per kt per wave. DS ops/kt/wave: 56 -> 20.
// Swapped operands reuse the SAME K/Q fragment registers (A/B per-lane
// geometry identical). O C-layout comes out identical to round 5, so the
// entire proven epilogue is unchanged (inv redistributed once via 8 shfl).
// Permlane output convention runtime-calibrated; __shfl_xor fallback.
// ---------------------------------------------------------------------------
union U4 { u32 u[4]; f16x8 v; };

template<bool UP>
__device__ __forceinline__ u32 ex16(u32 x, bool sel){
    if (UP) {
        u32 a = x, b = x;
        asm volatile("v_permlane16_swap_b32 %0, %1" : "+v"(a), "+v"(b));
        return sel ? a : b;
    }
    return (u32)__shfl_xor((int)x, 16);
}
template<bool UP>
__device__ __forceinline__ u32 ex32(u32 x, bool sel){
    if (UP) {
        u32 a = x, b = x;
        asm volatile("v_permlane32_swap_b32 %0, %1" : "+v"(a), "+v"(b));
        return sel ? a : b;
    }
    return (u32)__shfl_xor((int)x, 32);
}

// Build the PV A-fragment (8 f16, keys 32kc + 8*quad + j) from the swapped-QK
// pair words A0,A1 = pk[2kc][0..1], B0,B1 = pk[2kc+1][0..1].
// Routing verified per-word (see session notes r7): dest quad d pulls
// pk[2kc+(d>>1)][*] from src quads 2*(d&1), 2*(d&1)+1.
template<bool UP>
__device__ __forceinline__ f16x8 build_afrag(u32 A0, u32 A1, u32 B0, u32 B1,
                                             bool b4, bool b5, bool sel16, bool sel32){
    u32 Z0 = b5 ? B0 : A0, Z1 = b5 ? B1 : A1;   // serves dests q0,q3
    u32 W0 = b5 ? A0 : B0, W1 = b5 ? A1 : B1;   // serves dests q1,q2
    u32 xZ0 = ex16<UP>(Z0, sel16), xZ1 = ex16<UP>(Z1, sel16);
    u32 V0  = ex32<UP>(W0, sel32), V1  = ex32<UP>(W1, sel32);
    u32 X0  = ex16<UP>(V0, sel16), X1  = ex16<UP>(V1, sel16);
    U4 r;
    r.u[0] = b5 ? (b4 ? xZ0 : V0) : (b4 ? X0 : Z0);
    r.u[1] = b5 ? (b4 ? xZ1 : V1) : (b4 ? X1 : Z1);
    r.u[2] = b5 ? (b4 ? Z0 : X0) : (b4 ? V0 : xZ0);
    r.u[3] = b5 ? (b4 ? Z1 : X1) : (b4 ? V1 : xZ1);
    return r.v;
}

__device__ __forceinline__ u32 pkrtz(float a, float b){
    return __builtin_bit_cast(u32, __builtin_amdgcn_cvt_pkrtz(a, b));
}

template<bool UP>
__device__ __forceinline__ void attn_core(
    const u16* __restrict__ kh, const u16* __restrict__ vh,
    const float* __restrict__ Wo, float* __restrict__ out,
    u16* Klds, u16* Vlds, u16* PldsW,        // PldsW = &Plds[w][0][0]
    size_t base, size_t vbase,
    int tid, int w, int l15, int quad, int sw,
    int bh, int qt, bool b4m, bool b5m, bool sel16, bool sel32,
    const f16x8 (&aq)[2][2])
{
    f32x4 oacc[2][4];
    float lrun[2] = {0.f, 0.f};
    #pragma unroll
    for (int g = 0; g < 2; ++g)
        #pragma unroll
        for (int i = 0; i < 4; ++i)
            oacc[g][i] = (f32x4){0.f, 0.f, 0.f, 0.f};

    #pragma unroll 1
    for (int kt = 0; kt < 16; ++kt) {
        // ---- stage K rows + V^T rows, vectorized b128, swizzled ----
        #pragma unroll
        for (int i = 0; i < 2; ++i) {
            int ch = tid + 256 * i;          // 512 chunks of 8 u16
            int r = ch >> 3, cc = ch & 7;
            short8 kval = *(const short8*)(kh + base + (size_t)(kt * 64 + r) * 64 + cc * 8);
            *(short8*)&Klds[r * 64 + ((cc ^ (r & 7)) * 8)] = kval;
            short8 vval = *(const short8*)(vh + vbase + (size_t)r * T_ + kt * 64 + cc * 8);
            *(short8*)&Vlds[r * 64 + ((cc ^ (r & 7)) * 8)] = vval;
        }
        __syncthreads();

        // ---- swapped S^T = K Q^T: lane holds q=l15, keys 16u+quad*4+r ----
        u32 pk[2][4][2];
        #pragma unroll
        for (int u = 0; u < 4; ++u) {
            int row = 16 * u + l15;
            f16x8 bk0 = *(const f16x8*)&Klds[row * 64 + (((quad + 0) ^ sw) * 8)];
            f16x8 bk1 = *(const f16x8*)&Klds[row * 64 + (((quad + 4) ^ sw) * 8)];
            #pragma unroll
            for (int g = 0; g < 2; ++g) {
                f32x4 z = (f32x4){0.f, 0.f, 0.f, 0.f};
                z = MFMA16(bk0, aq[g][0], z);
                z = MFMA16(bk1, aq[g][1], z);
                float e0 = __expf(z[0]), e1 = __expf(z[1]);
                float e2 = __expf(z[2]), e3 = __expf(z[3]);
                lrun[g] += (e0 + e1) + (e2 + e3);
                pk[g][u][0] = pkrtz(e0, e1);
                pk[g][u][1] = pkrtz(e2, e3);
            }
        }

        // ---- O += P V with A-fragments built in-register ----
        #pragma unroll
        for (int kc = 0; kc < 2; ++kc) {
            f16x8 ap0 = build_afrag<UP>(pk[0][2*kc][0], pk[0][2*kc][1],
                                        pk[0][2*kc+1][0], pk[0][2*kc+1][1],
                                        b4m, b5m, sel16, sel32);
            f16x8 ap1 = build_afrag<UP>(pk[1][2*kc][0], pk[1][2*kc][1],
                                        pk[1][2*kc+1][0], pk[1][2*kc+1][1],
                                        b4m, b5m, sel16, sel32);
            int csel = ((quad + 4 * kc) ^ sw) * 8;
            #pragma unroll
            for (int nt = 0; nt < 4; ++nt) {
                f16x8 bv = *(const f16x8*)&Vlds[(16 * nt + l15) * 64 + csel];
                oacc[0][nt] = MFMA16(ap0, bv, oacc[0][nt]);
                oacc[1][nt] = MFMA16(ap1, bv, oacc[1][nt]);
            }
        }
        __syncthreads();
    }

    // ---- denominator: quad-butterfly, then redistribute to C-layout rows ----
    float invr[2][4];
    #pragma unroll
    for (int g = 0; g < 2; ++g) {
        float s = lrun[g];
        s += __shfl_xor(s, 16);
        s += __shfl_xor(s, 32);
        float iv = __builtin_amdgcn_rcpf(s);   // inv for q = l15
        #pragma unroll
        for (int r = 0; r < 4; ++r)
            invr[g][r] = __shfl(iv, quad * 4 + r, 16);   // inv for q = quad*4+r
    }

    // ---- fused output projection: out_tile = (O/l) * Wo[h] (round-5 path) ----
    const int b  = bh >> 4, hh = bh & 15;
    {
        const float* wo = Wo + (size_t)hh * D_ * D_;
        #pragma unroll
        for (int i = 0; i < 2; ++i) {
            int ch = tid + 256 * i;          // e = ch>>3, dc = ch&7
            int e = ch >> 3, dc = ch & 7;
            short8 vch;
            #pragma unroll
            for (int j = 0; j < 8; ++j)
                vch[j] = (short)f2h(wo[(size_t)(dc * 8 + j) * D_ + e]);
            *(short8*)&Klds[e * 64 + ((dc ^ (e & 7)) * 8)] = vch;
        }
    }
    #pragma unroll
    for (int g = 0; g < 2; ++g) {
        u16* Pw = PldsW + g * 16 * 64;
        #pragma unroll
        for (int nt = 0; nt < 4; ++nt) {
            int col = 16 * nt + l15;             // d
            #pragma unroll
            for (int r = 0; r < 4; ++r) {
                int row = quad * 4 + r;          // q
                Pw[row * 64 + (((col >> 3) ^ (row & 7)) * 8) + (col & 7)] =
                    f2h(oacc[g][nt][r] * invr[g][r]);
            }
        }
    }
    __syncthreads();    // Wo^T staging + O relayout visible

    f16x8 ao[2][2];
    #pragma unroll
    for (int g = 0; g < 2; ++g) {
        const u16* Pw = PldsW + g * 16 * 64;
        ao[g][0] = *(const f16x8*)&Pw[l15 * 64 + (((quad + 0) ^ sw) * 8)];
        ao[g][1] = *(const f16x8*)&Pw[l15 * 64 + (((quad + 4) ^ sw) * 8)];
    }
    f32x4 oo[2][4];
    #pragma unroll
    for (int g = 0; g < 2; ++g)
        #pragma unroll
        for (int nt = 0; nt < 4; ++nt)
            oo[g][nt] = (f32x4){0.f, 0.f, 0.f, 0.f};
    #pragma unroll
    for (int nt = 0; nt < 4; ++nt) {
        int erow = 16 * nt + l15;
        f16x8 b0 = *(const f16x8*)&Klds[erow * 64 + (((quad + 0) ^ (erow & 7)) * 8)];
        f16x8 b1 = *(const f16x8*)&Klds[erow * 64 + (((quad + 4) ^ (erow & 7)) * 8)];
        #pragma unroll
        for (int g = 0; g < 2; ++g) {
            oo[g][nt] = MFMA16(ao[g][0], b0, oo[g][nt]);
            oo[g][nt] = MFMA16(ao[g][1], b1, oo[g][nt]);
        }
    }
    #pragma unroll
    for (int g = 0; g < 2; ++g)
        #pragma unroll
        for (int nt = 0; nt < 4; ++nt)
            #pragma unroll
            for (int r = 0; r < 4; ++r) {
                int qg = qt * 128 + (w + 4 * g) * 16 + quad * 4 + r;
                int e  = 16 * nt + l15;
                out[((size_t)b * T_ + qg) * E_ + hh * D_ + e] = oo[g][nt][r];
            }
}

__global__ __launch_bounds__(256) void attn_kernel(
    const u16* __restrict__ qh,   // [bh][t][64] f16, pre-scaled 1/256
    const u16* __restrict__ kh,   // nw states [bh][t][64] f16
    const u16* __restrict__ vh,   // V^T [bh][d][t] f16
    const float* __restrict__ Wo, // [H][64][64] fp32
    float* __restrict__ out)      // [B][T][E] fp32
{
    __shared__ __align__(16) u16 Klds[64 * 64];        // keys; later Wo^T
    __shared__ __align__(16) u16 Vlds[64 * 64];        // V^T: row=d, col=key
    __shared__ __align__(16) u16 Plds[4][2][16 * 64];  // epilogue O relayout

    const int tid  = threadIdx.x;
    const int lane = tid & 63;
    const int w    = tid >> 6;
    const int l15  = lane & 15;
    const int quad = lane >> 4;
    const int sw   = lane & 7;
    const int bh   = blockIdx.y;
    const int qt   = blockIdx.x;
    const bool b4m = (quad & 1) != 0;
    const bool b5m = quad >= 2;

    const size_t base  = (size_t)bh * T_ * D_;
    const size_t vbase = (size_t)bh * D_ * T_;

    // permlane swap calibration (which output holds the partner's value)
    u32 cx = (u32)lane, cy = (u32)lane;
    asm volatile("v_permlane16_swap_b32 %0, %1" : "+v"(cx), "+v"(cy));
    const bool sel16 = (cx == (u32)(lane ^ 16));
    const bool ok16  = sel16 || (cy == (u32)(lane ^ 16));
    u32 dx = (u32)lane, dy = (u32)lane;
    asm volatile("v_permlane32_swap_b32 %0, %1" : "+v"(dx), "+v"(dy));
    const bool sel32 = (dx == (u32)(lane ^ 32));
    const bool ok32  = sel32 || (dy == (u32)(lane ^ 32));
    const bool ok    = __all(ok16 && ok32);

    // Q fragments for both 16-row groups (rows16 index = w + 4g); these serve
    // as the B operand of the swapped QK^T (identical per-lane geometry).
    f16x8 aq[2][2];
    #pragma unroll
    for (int g = 0; g < 2; ++g) {
        int qrow = qt * 128 + (w + 4 * g) * 16 + l15;
        const f16x8* qp = (const f16x8*)(qh + base + (size_t)qrow * 64 + quad * 8);
        aq[g][0] = qp[0];
        aq[g][1] = qp[4];
    }

    if (ok)
        attn_core<true >(kh, vh, Wo, out, Klds, Vlds, &Plds[w][0][0],
                         base, vbase, tid, w, l15, quad, sw,
                         bh, qt, b4m, b5m, sel16, sel32, aq);
    else
        attn_core<false>(kh, vh, Wo, out, Klds, Vlds, &Plds[w][0][0],
                         base, vbase, tid, w, l15, quad, sw,
                         bh, qt, b4m, b5m, sel16, sel32, aq);
}

// ---------------------------------------------------------------------------
extern "C" void kernel_launch(void* const* d_in, const int* in_sizes, int n_in,
                              void* d_out, int out_size, void* d_ws, size_t ws_size,
                              hipStream_t stream)
{
    const float* src = (const float*)d_in[0];
    const float* tgt = (const float*)d_in[1];
    const float* Wq  = (const float*)d_in[2];
    const float* Wv  = (const float*)d_in[3];
    const float* Wo  = (const float*)d_in[4];
    const float* Wih = (const float*)d_in[5];
    const float* Whh = (const float*)d_in[6];
    const float* bih = (const float*)d_in[7];
    const float* bhh = (const float*)d_in[8];
    float* out = (float*)d_out;

    char* ws = (char*)d_ws;
    u16* qh  = (u16*)(ws);                             // [bh][t][d] 16 MB
    u16* vh  = (u16*)(ws + (size_t)16 * 1024 * 1024);  // V^T [bh][d][t] 16 MB
    u16* nwh = (u16*)(ws + (size_t)32 * 1024 * 1024);  // [bh][t][d] 16 MB

    (void)in_sizes; (void)n_in; (void)out_size; (void)ws_size;

    proj_rnn_kernel<<<dim3(BH_ + 4096), 256, 0, stream>>>(
        src, tgt, Wq, Wv, Wih, Whh, bih, bhh, qh, vh, nwh);
    attn_kernel<<<dim3(8, BH_), 256, 0, stream>>>(qh, nwh, vh, Wo, out);
}

// Round 8
// 365.305 us; speedup vs baseline: 1.2611x; 1.0739x over previous
//
#include <hip/hip_runtime.h>

typedef unsigned short u16;
typedef short short8 __attribute__((ext_vector_type(8)));
typedef float f32x4 __attribute__((ext_vector_type(4)));
typedef _Float16 f16;
typedef f16 f16x2 __attribute__((ext_vector_type(2)));
typedef f16 f16x8 __attribute__((ext_vector_type(8)));

#define B_ 8
#define T_ 1024
#define E_ 1024
#define H_ 16
#define D_ 64
#define BH_ 128

__device__ __forceinline__ float ftanh(float x){
    x = fminf(8.0f, fmaxf(-8.0f, x));
    float e2 = __expf(2.0f * x);
    return 1.0f - 2.0f * __builtin_amdgcn_rcpf(e2 + 1.0f);
}

__device__ __forceinline__ u16 f2h(float x){
    union { f16 h; u16 u; } v; v.h = (f16)x; return v.u;
}

__device__ __forceinline__ float dot8(f16x8 a, f16x8 b, float acc){
#if __has_builtin(__builtin_amdgcn_fdot2)
    f16x2 a0 = {a[0],a[1]}, a1 = {a[2],a[3]}, a2 = {a[4],a[5]}, a3 = {a[6],a[7]};
    f16x2 b0 = {b[0],b[1]}, b1 = {b[2],b[3]}, b2 = {b[4],b[5]}, b3 = {b[6],b[7]};
    acc = __builtin_amdgcn_fdot2(a0, b0, acc, false);
    acc = __builtin_amdgcn_fdot2(a1, b1, acc, false);
    acc = __builtin_amdgcn_fdot2(a2, b2, acc, false);
    acc = __builtin_amdgcn_fdot2(a3, b3, acc, false);
#else
    #pragma unroll
    for (int i = 0; i < 8; ++i) acc += (float)a[i] * (float)b[i];
#endif
    return acc;
}

__device__ __forceinline__ f16x8 pack8(f32x4 a, f32x4 b){
    f16x8 r;
    r[0]=(f16)a[0]; r[1]=(f16)a[1]; r[2]=(f16)a[2]; r[3]=(f16)a[3];
    r[4]=(f16)b[0]; r[5]=(f16)b[1]; r[6]=(f16)b[2]; r[7]=(f16)b[3];
    return r;
}

// Opaque register pin: keeps recurrent weights VGPR-resident across the loop.
#define PIN8(x) do { f32x4 _t = __builtin_bit_cast(f32x4, x); \
                     asm volatile("" : "+v"(_t));             \
                     x = __builtin_bit_cast(f16x8, _t); } while (0)

#define MFMA16(a, b, c) __builtin_amdgcn_mfma_f32_16x16x32_f16(a, b, c, 0, 0, 0)

// ---------------------------------------------------------------------------
// Kernel 1: fused RNN (blocks 0..127) + q/v projection (blocks 128..).
// VERBATIM round-0 RNN (217us = 1023 x ~504cy): best of {LDS-broadcast 217,
// DPP 235, setprio 230, MFMA-matvec 306}. Accepted as this structure's floor.
// ---------------------------------------------------------------------------
__global__ __launch_bounds__(256, 1) void proj_rnn_kernel(
    const float* __restrict__ src, const float* __restrict__ tgt,
    const float* __restrict__ Wq,  const float* __restrict__ Wv,
    const float* __restrict__ Wih, const float* __restrict__ Whh,
    const float* __restrict__ bih, const float* __restrict__ bhh,
    u16* __restrict__ qh, u16* __restrict__ vh, u16* __restrict__ nwh)
{
    int bid = blockIdx.x;
    if (bid < BH_) {
        if (threadIdx.x >= 64) return;
        __shared__ __align__(16) u16 hl[D_];
        const int b = bid >> 4, h = bid & 15;
        const int e = threadIdx.x;

        const f32x4* wi4 = (const f32x4*)(Wih + ((size_t)h * D_ + e) * D_);
        const f32x4* wh4 = (const f32x4*)(Whh + ((size_t)h * D_ + e) * D_);
        float c = bih[h * D_ + e] + bhh[h * D_ + e];
        asm volatile("" : "+v"(c));

        f16x8 n0 = pack8(wi4[0],  wi4[1]),  n1 = pack8(wi4[2],  wi4[3]);
        f16x8 n2 = pack8(wi4[4],  wi4[5]),  n3 = pack8(wi4[6],  wi4[7]);
        f16x8 n4 = pack8(wi4[8],  wi4[9]),  n5 = pack8(wi4[10], wi4[11]);
        f16x8 n6 = pack8(wi4[12], wi4[13]), n7 = pack8(wi4[14], wi4[15]);
        f16x8 m0 = pack8(wi4[0]+wh4[0],   wi4[1]+wh4[1]);
        f16x8 m1 = pack8(wi4[2]+wh4[2],   wi4[3]+wh4[3]);
        f16x8 m2 = pack8(wi4[4]+wh4[4],   wi4[5]+wh4[5]);
        f16x8 m3 = pack8(wi4[6]+wh4[6],   wi4[7]+wh4[7]);
        f16x8 m4 = pack8(wi4[8]+wh4[8],   wi4[9]+wh4[9]);
        f16x8 m5 = pack8(wi4[10]+wh4[10], wi4[11]+wh4[11]);
        f16x8 m6 = pack8(wi4[12]+wh4[12], wi4[13]+wh4[13]);
        f16x8 m7 = pack8(wi4[14]+wh4[14], wi4[15]+wh4[15]);
        PIN8(m0); PIN8(m1); PIN8(m2); PIN8(m3);
        PIN8(m4); PIN8(m5); PIN8(m6); PIN8(m7);

        hl[e] = f2h(tgt[(size_t)b * T_ * E_ + h * D_ + e]);  // k0

        u16* nwp = nwh + (size_t)bid * T_ * D_;
        const f16x8* hl8 = (const f16x8*)hl;

        {
            f16x8 x0=hl8[0],x1=hl8[1],x2=hl8[2],x3=hl8[3],
                  x4=hl8[4],x5=hl8[5],x6=hl8[6],x7=hl8[7];
            float s0=dot8(n0,x0,c),   s1=dot8(n1,x1,0.f),
                  s2=dot8(n2,x2,0.f), s3=dot8(n3,x3,0.f),
                  s4=dot8(n4,x4,0.f), s5=dot8(n5,x5,0.f),
                  s6=dot8(n6,x6,0.f), s7=dot8(n7,x7,0.f);
            float hv = ftanh(((s0+s1)+(s2+s3)) + ((s4+s5)+(s6+s7)));
            u16 hb = f2h(hv);
            hl[e] = hb;
            nwp[e] = hb;
        }

        #pragma unroll 1
        for (int t = 1; t < T_; ++t) {
            f16x8 x0=hl8[0],x1=hl8[1],x2=hl8[2],x3=hl8[3],
                  x4=hl8[4],x5=hl8[5],x6=hl8[6],x7=hl8[7];
            float s0=dot8(m0,x0,c),   s1=dot8(m1,x1,0.f),
                  s2=dot8(m2,x2,0.f), s3=dot8(m3,x3,0.f),
                  s4=dot8(m4,x4,0.f), s5=dot8(m5,x5,0.f),
                  s6=dot8(m6,x6,0.f), s7=dot8(m7,x7,0.f);
            float hv = ftanh(((s0+s1)+(s2+s3)) + ((s4+s5)+(s6+s7)));
            u16 hb = f2h(hv);
            hl[e] = hb;
            nwp[(size_t)t * D_ + e] = hb;
        }
    } else {
        int pb   = bid - BH_;          // 0 .. 4095
        int bh   = pb >> 5;            // (b*16+h)
        int tile = pb & 31;            // 32 t-rows per block
        int b = bh >> 4, h = bh & 15;
        int e  = threadIdx.x & 63;
        int tg = threadIdx.x >> 6;
        int t0 = tile * 32 + tg * 8;

        const float* wq = Wq + (size_t)h * D_ * D_ + e;  // column e, stride 64
        const float* wv = Wv + (size_t)h * D_ * D_ + e;
        const float* s0 = src + ((size_t)b * T_ + t0) * E_ + h * D_;
        const float* g0 = tgt + ((size_t)b * T_ + t0) * E_ + h * D_;

        float aq[8] = {0,0,0,0,0,0,0,0};
        float av[8] = {0,0,0,0,0,0,0,0};
        #pragma unroll 4
        for (int d4 = 0; d4 < 16; ++d4) {
            float q0 = wq[(4*d4+0)*64], q1 = wq[(4*d4+1)*64],
                  q2 = wq[(4*d4+2)*64], q3 = wq[(4*d4+3)*64];
            float v0 = wv[(4*d4+0)*64], v1 = wv[(4*d4+1)*64],
                  v2 = wv[(4*d4+2)*64], v3 = wv[(4*d4+3)*64];
            #pragma unroll
            for (int j = 0; j < 8; ++j) {
                float4 x = *(const float4*)(s0 + (size_t)j * E_ + 4*d4);
                float4 y = *(const float4*)(g0 + (size_t)j * E_ + 4*d4);
                aq[j] += x.x*q0 + x.y*q1 + x.z*q2 + x.w*q3;
                av[j] += y.x*v0 + y.y*v1 + y.z*v2 + y.w*v3;
            }
        }
        u16* qp = qh + ((size_t)bh * T_ + t0) * D_ + e;
        #pragma unroll
        for (int j = 0; j < 8; ++j) qp[(size_t)j * D_] = f2h(aq[j] * (1.0f/256.0f));
        f16x8 vv;
        #pragma unroll
        for (int j = 0; j < 8; ++j) vv[j] = (f16)av[j];
        *(f16x8*)(vh + ((size_t)bh * D_ + e) * T_ + t0) = vv;
    }
}

// ---------------------------------------------------------------------------
// Kernel 2: flash attention. Round-8: round-5 compute path (proven best; the
// round-7 in-register P-exchange A/B showed attn is issue-bound, not DS-bound)
// with TWO structural changes:
//  - double-buffered K/V: global loads for kt+1 issued at top of iter (latency
//    hidden under compute), committed to buf[cur^1] after compute, ONE barrier
//    per kt (was 2).
//  - grid dim3(128,8): bh on fast axis -> flatId%8 = bh%8, so all 8 qt-blocks
//    of one bh land on the same XCD; its 16 bh x 256KB K/V fit the 4MB L2.
//  - Plds single-buffer per wave (epilogue g-loop serialized, wave-local) to
//    keep LDS at 40KB = 4 blocks/CU.
// ---------------------------------------------------------------------------
__global__ __launch_bounds__(256) void attn_kernel(
    const u16* __restrict__ qh,   // [bh][t][64] f16, pre-scaled 1/256
    const u16* __restrict__ kh,   // nw states [bh][t][64] f16
    const u16* __restrict__ vh,   // V^T [bh][d][t] f16
    const float* __restrict__ Wo, // [H][64][64] fp32
    float* __restrict__ out)      // [B][T][E] fp32
{
    __shared__ __align__(16) u16 Klds[2][64 * 64];  // keys dbuf; [0] later Wo^T
    __shared__ __align__(16) u16 Vlds[2][64 * 64];  // V^T dbuf: row=d, col=key
    __shared__ __align__(16) u16 Plds[4][16 * 64];  // per-wave P / O relayout

    const int tid  = threadIdx.x;
    const int lane = tid & 63;
    const int w    = tid >> 6;
    const int l15  = lane & 15;
    const int quad = lane >> 4;
    const int sw   = lane & 7;
    const int bh   = blockIdx.x;   // fast axis: XCD co-location per bh
    const int qt   = blockIdx.y;

    const size_t base  = (size_t)bh * T_ * D_;
    const size_t vbase = (size_t)bh * D_ * T_;

    // Q fragments for both 16-row groups (rows16 index = w + 4g)
    f16x8 aq[2][2];
    #pragma unroll
    for (int g = 0; g < 2; ++g) {
        int qrow = qt * 128 + (w + 4 * g) * 16 + l15;
        const f16x8* qp = (const f16x8*)(qh + base + (size_t)qrow * 64 + quad * 8);
        aq[g][0] = qp[0];
        aq[g][1] = qp[4];
    }

    f32x4 oacc[2][4];
    float lrun[2][4];
    #pragma unroll
    for (int g = 0; g < 2; ++g)
        #pragma unroll
        for (int i = 0; i < 4; ++i) {
            oacc[g][i] = (f32x4){0.f, 0.f, 0.f, 0.f};
            lrun[g][i] = 0.f;
        }

    // ---- prologue: stage tile 0 ----
    #pragma unroll
    for (int i = 0; i < 2; ++i) {
        int ch = tid + 256 * i;              // 512 chunks of 8 u16
        int r = ch >> 3, cc = ch & 7;
        short8 kval = *(const short8*)(kh + base + (size_t)r * 64 + cc * 8);
        *(short8*)&Klds[0][r * 64 + ((cc ^ (r & 7)) * 8)] = kval;
        short8 vval = *(const short8*)(vh + vbase + (size_t)r * T_ + cc * 8);
        *(short8*)&Vlds[0][r * 64 + ((cc ^ (r & 7)) * 8)] = vval;
    }
    __syncthreads();

    #pragma unroll 1
    for (int kt = 0; kt < 16; ++kt) {
        const int cur = kt & 1;

        // ---- prefetch kt+1 into registers (hides under compute) ----
        short8 kpre[2], vpre[2];
        if (kt < 15) {
            #pragma unroll
            for (int i = 0; i < 2; ++i) {
                int ch = tid + 256 * i;
                int r = ch >> 3, cc = ch & 7;
                kpre[i] = *(const short8*)(kh + base + (size_t)((kt + 1) * 64 + r) * 64 + cc * 8);
                vpre[i] = *(const short8*)(vh + vbase + (size_t)r * T_ + (kt + 1) * 64 + cc * 8);
            }
        }

        const u16* Kb = Klds[cur];
        const u16* Vb = Vlds[cur];

        // ---- S = Q K^T, K-fragments shared across both q-groups ----
        f32x4 sacc[2][4];
        #pragma unroll
        for (int u = 0; u < 4; ++u) {
            int row = 16 * u + l15;
            f16x8 bk0 = *(const f16x8*)&Kb[row * 64 + (((quad + 0) ^ sw) * 8)];
            f16x8 bk1 = *(const f16x8*)&Kb[row * 64 + (((quad + 4) ^ sw) * 8)];
            #pragma unroll
            for (int g = 0; g < 2; ++g) {
                f32x4 z = (f32x4){0.f, 0.f, 0.f, 0.f};
                z = MFMA16(aq[g][0], bk0, z);
                z = MFMA16(aq[g][1], bk1, z);
                sacc[g][u] = z;
            }
        }

        // ---- softmax: exp + lane-local partial sums (reduce deferred) ----
        #pragma unroll
        for (int g = 0; g < 2; ++g) {
            float pr[4][4];
            #pragma unroll
            for (int r = 0; r < 4; ++r) {
                float rs = 0.f;
                #pragma unroll
                for (int u = 0; u < 4; ++u) {
                    float pv = __expf(sacc[g][u][r]);
                    pr[u][r] = pv;
                    rs += pv;
                }
                lrun[g][r] += rs;
            }
            // P -> per-wave LDS (C-layout -> A-fragment layout); wave-local
            u16* Pw = Plds[w];
            #pragma unroll
            for (int u = 0; u < 4; ++u) {
                int col = 16 * u + l15;
                #pragma unroll
                for (int r = 0; r < 4; ++r) {
                    int row = quad * 4 + r;
                    Pw[row * 64 + (((col >> 3) ^ (row & 7)) * 8) + (col & 7)] = f2h(pr[u][r]);
                }
            }
            // ---- O += P V for this group (Pw reused across groups) ----
            #pragma unroll
            for (int kc = 0; kc < 2; ++kc) {
                int csel = ((quad + 4 * kc) ^ sw) * 8;
                f16x8 ap = *(const f16x8*)&Pw[l15 * 64 + csel];
                #pragma unroll
                for (int nt = 0; nt < 4; ++nt) {
                    f16x8 bv = *(const f16x8*)&Vb[(16 * nt + l15) * 64 + csel];
                    oacc[g][nt] = MFMA16(ap, bv, oacc[g][nt]);
                }
            }
        }

        // ---- commit prefetched tile ----
        if (kt < 15) {
            const int nxt = cur ^ 1;
            #pragma unroll
            for (int i = 0; i < 2; ++i) {
                int ch = tid + 256 * i;
                int r = ch >> 3, cc = ch & 7;
                *(short8*)&Klds[nxt][r * 64 + ((cc ^ (r & 7)) * 8)] = kpre[i];
                *(short8*)&Vlds[nxt][r * 64 + ((cc ^ (r & 7)) * 8)] = vpre[i];
            }
        }
        __syncthreads();   // single barrier per kt
    }

    // ---- deferred denominator: one 16-lane reduce per (g, r) ----
    float inv[2][4];
    #pragma unroll
    for (int g = 0; g < 2; ++g)
        #pragma unroll
        for (int r = 0; r < 4; ++r) {
            float s = lrun[g][r];
            #pragma unroll
            for (int off = 1; off < 16; off <<= 1)
                s += __shfl_xor(s, off, 16);
            inv[g][r] = __builtin_amdgcn_rcpf(s);
        }

    // ---- fused output projection: out_tile = (O/l) * Wo[h] ----
    const int b  = bh >> 4, hh = bh & 15;
    {
        const float* wo = Wo + (size_t)hh * D_ * D_;
        #pragma unroll
        for (int i = 0; i < 2; ++i) {
            int ch = tid + 256 * i;          // e = ch>>3, dc = ch&7
            int e = ch >> 3, dc = ch & 7;
            short8 vch;
            #pragma unroll
            for (int j = 0; j < 8; ++j)
                vch[j] = (short)f2h(wo[(size_t)(dc * 8 + j) * D_ + e]);
            *(short8*)&Klds[0][e * 64 + ((dc ^ (e & 7)) * 8)] = vch;
        }
    }
    // O relayout + A-fragment reads, serialized over g (wave-local Pw reuse)
    f16x8 ao[2][2];
    {
        u16* Pw = Plds[w];
        #pragma unroll
        for (int g = 0; g < 2; ++g) {
            #pragma unroll
            for (int nt = 0; nt < 4; ++nt) {
                int col = 16 * nt + l15;             // d
                #pragma unroll
                for (int r = 0; r < 4; ++r) {
                    int row = quad * 4 + r;          // q
                    Pw[row * 64 + (((col >> 3) ^ (row & 7)) * 8) + (col & 7)] =
                        f2h(oacc[g][nt][r] * inv[g][r]);
                }
            }
            ao[g][0] = *(const f16x8*)&Pw[l15 * 64 + (((quad + 0) ^ sw) * 8)];
            ao[g][1] = *(const f16x8*)&Pw[l15 * 64 + (((quad + 4) ^ sw) * 8)];
        }
    }
    __syncthreads();    // Wo^T staging visible to all waves

    f32x4 oo[2][4];
    #pragma unroll
    for (int g = 0; g < 2; ++g)
        #pragma unroll
        for (int nt = 0; nt < 4; ++nt)
            oo[g][nt] = (f32x4){0.f, 0.f, 0.f, 0.f};
    #pragma unroll
    for (int nt = 0; nt < 4; ++nt) {
        int erow = 16 * nt + l15;
        f16x8 b0 = *(const f16x8*)&Klds[0][erow * 64 + (((quad + 0) ^ (erow & 7)) * 8)];
        f16x8 b1 = *(const f16x8*)&Klds[0][erow * 64 + (((quad + 4) ^ (erow & 7)) * 8)];
        #pragma unroll
        for (int g = 0; g < 2; ++g) {
            oo[g][nt] = MFMA16(ao[g][0], b0, oo[g][nt]);
            oo[g][nt] = MFMA16(ao[g][1], b1, oo[g][nt]);
        }
    }
    #pragma unroll
    for (int g = 0; g < 2; ++g)
        #pragma unroll
        for (int nt = 0; nt < 4; ++nt)
            #pragma unroll
            for (int r = 0; r < 4; ++r) {
                int qg = qt * 128 + (w + 4 * g) * 16 + quad * 4 + r;
                int e  = 16 * nt + l15;
                out[((size_t)b * T_ + qg) * E_ + hh * D_ + e] = oo[g][nt][r];
            }
}

// ---------------------------------------------------------------------------
extern "C" void kernel_launch(void* const* d_in, const int* in_sizes, int n_in,
                              void* d_out, int out_size, void* d_ws, size_t ws_size,
                              hipStream_t stream)
{
    const float* src = (const float*)d_in[0];
    const float* tgt = (const float*)d_in[1];
    const float* Wq  = (const float*)d_in[2];
    const float* Wv  = (const float*)d_in[3];
    const float* Wo  = (const float*)d_in[4];
    const float* Wih = (const float*)d_in[5];
    const float* Whh = (const float*)d_in[6];
    const float* bih = (const float*)d_in[7];
    const float* bhh = (const float*)d_in[8];
    float* out = (float*)d_out;

    char* ws = (char*)d_ws;
    u16* qh  = (u16*)(ws);                             // [bh][t][d] 16 MB
    u16* vh  = (u16*)(ws + (size_t)16 * 1024 * 1024);  // V^T [bh][d][t] 16 MB
    u16* nwh = (u16*)(ws + (size_t)32 * 1024 * 1024);  // [bh][t][d] 16 MB

    (void)in_sizes; (void)n_in; (void)out_size; (void)ws_size;

    proj_rnn_kernel<<<dim3(BH_ + 4096), 256, 0, stream>>>(
        src, tgt, Wq, Wv, Wih, Whh, bih, bhh, qh, vh, nwh);
    // bh on the FAST grid axis: all 8 qt-blocks of a bh share an XCD (L2 reuse)
    attn_kernel<<<dim3(BH_, 8), 256, 0, stream>>>(qh, nwh, vh, Wo, out);
}

// Round 10
// 365.042 us; speedup vs baseline: 1.2620x; 1.0007x over previous
//
#include <hip/hip_runtime.h>

typedef unsigned short u16;
typedef short short8 __attribute__((ext_vector_type(8)));
typedef float f32x4 __attribute__((ext_vector_type(4)));
typedef _Float16 f16;
typedef f16 f16x2 __attribute__((ext_vector_type(2)));
typedef f16 f16x8 __attribute__((ext_vector_type(8)));

#define B_ 8
#define T_ 1024
#define E_ 1024
#define H_ 16
#define D_ 64
#define BH_ 128

// ---------------------------------------------------------------------------
// SESSION LEDGER (rounds 0-9):
//  - RNN step-mechanism variants: LDS-broadcast 217us (BEST) / DPP 235 /
//    setprio 230 / MFMA-matvec 306. ~500cy/step is the structural floor of a
//    lone-wave serial chain; not issue-contention (r2), not broadcast (r1).
//  - Attn: round-5 amortized structure (128 q-rows, shared K/V frags,
//    deferred denom) + round-8 dbuf/1-barrier/XCD-swizzle = 150us (BEST).
//    In-register P-exchange (r7) regressed: attn is issue-bound, not DS-bound.
//  - Cross-XCD RNN->attn streaming: CLOSED. Acquire-polling correct but
//    +270us (L2 invalidation storm, r3); relaxed-polling never observes
//    flags -> timeout hang, container kill (r9). Relaxed atomic LOADS do not
//    bypass stale local caches on gfx950; only RMW/acquire do.
// This file == round-8 kernel (365.3us, absmax 1.2e-4), the proven best.
// ---------------------------------------------------------------------------

__device__ __forceinline__ float ftanh(float x){
    x = fminf(8.0f, fmaxf(-8.0f, x));
    float e2 = __expf(2.0f * x);
    return 1.0f - 2.0f * __builtin_amdgcn_rcpf(e2 + 1.0f);
}

__device__ __forceinline__ u16 f2h(float x){
    union { f16 h; u16 u; } v; v.h = (f16)x; return v.u;
}

__device__ __forceinline__ float dot8(f16x8 a, f16x8 b, float acc){
#if __has_builtin(__builtin_amdgcn_fdot2)
    f16x2 a0 = {a[0],a[1]}, a1 = {a[2],a[3]}, a2 = {a[4],a[5]}, a3 = {a[6],a[7]};
    f16x2 b0 = {b[0],b[1]}, b1 = {b[2],b[3]}, b2 = {b[4],b[5]}, b3 = {b[6],b[7]};
    acc = __builtin_amdgcn_fdot2(a0, b0, acc, false);
    acc = __builtin_amdgcn_fdot2(a1, b1, acc, false);
    acc = __builtin_amdgcn_fdot2(a2, b2, acc, false);
    acc = __builtin_amdgcn_fdot2(a3, b3, acc, false);
#else
    #pragma unroll
    for (int i = 0; i < 8; ++i) acc += (float)a[i] * (float)b[i];
#endif
    return acc;
}

__device__ __forceinline__ f16x8 pack8(f32x4 a, f32x4 b){
    f16x8 r;
    r[0]=(f16)a[0]; r[1]=(f16)a[1]; r[2]=(f16)a[2]; r[3]=(f16)a[3];
    r[4]=(f16)b[0]; r[5]=(f16)b[1]; r[6]=(f16)b[2]; r[7]=(f16)b[3];
    return r;
}

// Opaque register pin: keeps recurrent weights VGPR-resident across the loop.
#define PIN8(x) do { f32x4 _t = __builtin_bit_cast(f32x4, x); \
                     asm volatile("" : "+v"(_t));             \
                     x = __builtin_bit_cast(f16x8, _t); } while (0)

#define MFMA16(a, b, c) __builtin_amdgcn_mfma_f32_16x16x32_f16(a, b, c, 0, 0, 0)

// ---------------------------------------------------------------------------
// Kernel 1: fused RNN (blocks 0..127) + q/v projection (blocks 128..).
// ---------------------------------------------------------------------------
__global__ __launch_bounds__(256, 1) void proj_rnn_kernel(
    const float* __restrict__ src, const float* __restrict__ tgt,
    const float* __restrict__ Wq,  const float* __restrict__ Wv,
    const float* __restrict__ Wih, const float* __restrict__ Whh,
    const float* __restrict__ bih, const float* __restrict__ bhh,
    u16* __restrict__ qh, u16* __restrict__ vh, u16* __restrict__ nwh)
{
    int bid = blockIdx.x;
    if (bid < BH_) {
        if (threadIdx.x >= 64) return;
        __shared__ __align__(16) u16 hl[D_];
        const int b = bid >> 4, h = bid & 15;
        const int e = threadIdx.x;

        const f32x4* wi4 = (const f32x4*)(Wih + ((size_t)h * D_ + e) * D_);
        const f32x4* wh4 = (const f32x4*)(Whh + ((size_t)h * D_ + e) * D_);
        float c = bih[h * D_ + e] + bhh[h * D_ + e];
        asm volatile("" : "+v"(c));

        f16x8 n0 = pack8(wi4[0],  wi4[1]),  n1 = pack8(wi4[2],  wi4[3]);
        f16x8 n2 = pack8(wi4[4],  wi4[5]),  n3 = pack8(wi4[6],  wi4[7]);
        f16x8 n4 = pack8(wi4[8],  wi4[9]),  n5 = pack8(wi4[10], wi4[11]);
        f16x8 n6 = pack8(wi4[12], wi4[13]), n7 = pack8(wi4[14], wi4[15]);
        f16x8 m0 = pack8(wi4[0]+wh4[0],   wi4[1]+wh4[1]);
        f16x8 m1 = pack8(wi4[2]+wh4[2],   wi4[3]+wh4[3]);
        f16x8 m2 = pack8(wi4[4]+wh4[4],   wi4[5]+wh4[5]);
        f16x8 m3 = pack8(wi4[6]+wh4[6],   wi4[7]+wh4[7]);
        f16x8 m4 = pack8(wi4[8]+wh4[8],   wi4[9]+wh4[9]);
        f16x8 m5 = pack8(wi4[10]+wh4[10], wi4[11]+wh4[11]);
        f16x8 m6 = pack8(wi4[12]+wh4[12], wi4[13]+wh4[13]);
        f16x8 m7 = pack8(wi4[14]+wh4[14], wi4[15]+wh4[15]);
        PIN8(m0); PIN8(m1); PIN8(m2); PIN8(m3);
        PIN8(m4); PIN8(m5); PIN8(m6); PIN8(m7);

        hl[e] = f2h(tgt[(size_t)b * T_ * E_ + h * D_ + e]);  // k0

        u16* nwp = nwh + (size_t)bid * T_ * D_;
        const f16x8* hl8 = (const f16x8*)hl;

        {
            f16x8 x0=hl8[0],x1=hl8[1],x2=hl8[2],x3=hl8[3],
                  x4=hl8[4],x5=hl8[5],x6=hl8[6],x7=hl8[7];
            float s0=dot8(n0,x0,c),   s1=dot8(n1,x1,0.f),
                  s2=dot8(n2,x2,0.f), s3=dot8(n3,x3,0.f),
                  s4=dot8(n4,x4,0.f), s5=dot8(n5,x5,0.f),
                  s6=dot8(n6,x6,0.f), s7=dot8(n7,x7,0.f);
            float hv = ftanh(((s0+s1)+(s2+s3)) + ((s4+s5)+(s6+s7)));
            u16 hb = f2h(hv);
            hl[e] = hb;
            nwp[e] = hb;
        }

        #pragma unroll 1
        for (int t = 1; t < T_; ++t) {
            f16x8 x0=hl8[0],x1=hl8[1],x2=hl8[2],x3=hl8[3],
                  x4=hl8[4],x5=hl8[5],x6=hl8[6],x7=hl8[7];
            float s0=dot8(m0,x0,c),   s1=dot8(m1,x1,0.f),
                  s2=dot8(m2,x2,0.f), s3=dot8(m3,x3,0.f),
                  s4=dot8(m4,x4,0.f), s5=dot8(m5,x5,0.f),
                  s6=dot8(m6,x6,0.f), s7=dot8(m7,x7,0.f);
            float hv = ftanh(((s0+s1)+(s2+s3)) + ((s4+s5)+(s6+s7)));
            u16 hb = f2h(hv);
            hl[e] = hb;
            nwp[(size_t)t * D_ + e] = hb;
        }
    } else {
        int pb   = bid - BH_;          // 0 .. 4095
        int bh   = pb >> 5;            // (b*16+h)
        int tile = pb & 31;            // 32 t-rows per block
        int b = bh >> 4, h = bh & 15;
        int e  = threadIdx.x & 63;
        int tg = threadIdx.x >> 6;
        int t0 = tile * 32 + tg * 8;

        const float* wq = Wq + (size_t)h * D_ * D_ + e;  // column e, stride 64
        const float* wv = Wv + (size_t)h * D_ * D_ + e;
        const float* s0 = src + ((size_t)b * T_ + t0) * E_ + h * D_;
        const float* g0 = tgt + ((size_t)b * T_ + t0) * E_ + h * D_;

        float aq[8] = {0,0,0,0,0,0,0,0};
        float av[8] = {0,0,0,0,0,0,0,0};
        #pragma unroll 4
        for (int d4 = 0; d4 < 16; ++d4) {
            float q0 = wq[(4*d4+0)*64], q1 = wq[(4*d4+1)*64],
                  q2 = wq[(4*d4+2)*64], q3 = wq[(4*d4+3)*64];
            float v0 = wv[(4*d4+0)*64], v1 = wv[(4*d4+1)*64],
                  v2 = wv[(4*d4+2)*64], v3 = wv[(4*d4+3)*64];
            #pragma unroll
            for (int j = 0; j < 8; ++j) {
                float4 x = *(const float4*)(s0 + (size_t)j * E_ + 4*d4);
                float4 y = *(const float4*)(g0 + (size_t)j * E_ + 4*d4);
                aq[j] += x.x*q0 + x.y*q1 + x.z*q2 + x.w*q3;
                av[j] += y.x*v0 + y.y*v1 + y.z*v2 + y.w*v3;
            }
        }
        u16* qp = qh + ((size_t)bh * T_ + t0) * D_ + e;
        #pragma unroll
        for (int j = 0; j < 8; ++j) qp[(size_t)j * D_] = f2h(aq[j] * (1.0f/256.0f));
        f16x8 vv;
        #pragma unroll
        for (int j = 0; j < 8; ++j) vv[j] = (f16)av[j];
        *(f16x8*)(vh + ((size_t)bh * D_ + e) * T_ + t0) = vv;
    }
}

// ---------------------------------------------------------------------------
// Kernel 2: flash attention (round-8 form: round-5 compute path + dbuf K/V
// with one barrier per kt + bh-fast grid axis for XCD L2 co-location).
// ---------------------------------------------------------------------------
__global__ __launch_bounds__(256) void attn_kernel(
    const u16* __restrict__ qh,   // [bh][t][64] f16, pre-scaled 1/256
    const u16* __restrict__ kh,   // nw states [bh][t][64] f16
    const u16* __restrict__ vh,   // V^T [bh][d][t] f16
    const float* __restrict__ Wo, // [H][64][64] fp32
    float* __restrict__ out)      // [B][T][E] fp32
{
    __shared__ __align__(16) u16 Klds[2][64 * 64];  // keys dbuf; [0] later Wo^T
    __shared__ __align__(16) u16 Vlds[2][64 * 64];  // V^T dbuf: row=d, col=key
    __shared__ __align__(16) u16 Plds[4][16 * 64];  // per-wave P / O relayout

    const int tid  = threadIdx.x;
    const int lane = tid & 63;
    const int w    = tid >> 6;
    const int l15  = lane & 15;
    const int quad = lane >> 4;
    const int sw   = lane & 7;
    const int bh   = blockIdx.x;   // fast axis: XCD co-location per bh
    const int qt   = blockIdx.y;

    const size_t base  = (size_t)bh * T_ * D_;
    const size_t vbase = (size_t)bh * D_ * T_;

    // Q fragments for both 16-row groups (rows16 index = w + 4g)
    f16x8 aq[2][2];
    #pragma unroll
    for (int g = 0; g < 2; ++g) {
        int qrow = qt * 128 + (w + 4 * g) * 16 + l15;
        const f16x8* qp = (const f16x8*)(qh + base + (size_t)qrow * 64 + quad * 8);
        aq[g][0] = qp[0];
        aq[g][1] = qp[4];
    }

    f32x4 oacc[2][4];
    float lrun[2][4];
    #pragma unroll
    for (int g = 0; g < 2; ++g)
        #pragma unroll
        for (int i = 0; i < 4; ++i) {
            oacc[g][i] = (f32x4){0.f, 0.f, 0.f, 0.f};
            lrun[g][i] = 0.f;
        }

    // ---- prologue: stage tile 0 ----
    #pragma unroll
    for (int i = 0; i < 2; ++i) {
        int ch = tid + 256 * i;              // 512 chunks of 8 u16
        int r = ch >> 3, cc = ch & 7;
        short8 kval = *(const short8*)(kh + base + (size_t)r * 64 + cc * 8);
        *(short8*)&Klds[0][r * 64 + ((cc ^ (r & 7)) * 8)] = kval;
        short8 vval = *(const short8*)(vh + vbase + (size_t)r * T_ + cc * 8);
        *(short8*)&Vlds[0][r * 64 + ((cc ^ (r & 7)) * 8)] = vval;
    }
    __syncthreads();

    #pragma unroll 1
    for (int kt = 0; kt < 16; ++kt) {
        const int cur = kt & 1;

        // ---- prefetch kt+1 into registers (hides under compute) ----
        short8 kpre[2], vpre[2];
        if (kt < 15) {
            #pragma unroll
            for (int i = 0; i < 2; ++i) {
                int ch = tid + 256 * i;
                int r = ch >> 3, cc = ch & 7;
                kpre[i] = *(const short8*)(kh + base + (size_t)((kt + 1) * 64 + r) * 64 + cc * 8);
                vpre[i] = *(const short8*)(vh + vbase + (size_t)r * T_ + (kt + 1) * 64 + cc * 8);
            }
        }

        const u16* Kb = Klds[cur];
        const u16* Vb = Vlds[cur];

        // ---- S = Q K^T, K-fragments shared across both q-groups ----
        f32x4 sacc[2][4];
        #pragma unroll
        for (int u = 0; u < 4; ++u) {
            int row = 16 * u + l15;
            f16x8 bk0 = *(const f16x8*)&Kb[row * 64 + (((quad + 0) ^ sw) * 8)];
            f16x8 bk1 = *(const f16x8*)&Kb[row * 64 + (((quad + 4) ^ sw) * 8)];
            #pragma unroll
            for (int g = 0; g < 2; ++g) {
                f32x4 z = (f32x4){0.f, 0.f, 0.f, 0.f};
                z = MFMA16(aq[g][0], bk0, z);
                z = MFMA16(aq[g][1], bk1, z);
                sacc[g][u] = z;
            }
        }

        // ---- softmax: exp + lane-local partial sums (reduce deferred) ----
        #pragma unroll
        for (int g = 0; g < 2; ++g) {
            float pr[4][4];
            #pragma unroll
            for (int r = 0; r < 4; ++r) {
                float rs = 0.f;
                #pragma unroll
                for (int u = 0; u < 4; ++u) {
                    float pv = __expf(sacc[g][u][r]);
                    pr[u][r] = pv;
                    rs += pv;
                }
                lrun[g][r] += rs;
            }
            // P -> per-wave LDS (C-layout -> A-fragment layout); wave-local
            u16* Pw = Plds[w];
            #pragma unroll
            for (int u = 0; u < 4; ++u) {
                int col = 16 * u + l15;
                #pragma unroll
                for (int r = 0; r < 4; ++r) {
                    int row = quad * 4 + r;
                    Pw[row * 64 + (((col >> 3) ^ (row & 7)) * 8) + (col & 7)] = f2h(pr[u][r]);
                }
            }
            // ---- O += P V for this group (Pw reused across groups) ----
            #pragma unroll
            for (int kc = 0; kc < 2; ++kc) {
                int csel = ((quad + 4 * kc) ^ sw) * 8;
                f16x8 ap = *(const f16x8*)&Pw[l15 * 64 + csel];
                #pragma unroll
                for (int nt = 0; nt < 4; ++nt) {
                    f16x8 bv = *(const f16x8*)&Vb[(16 * nt + l15) * 64 + csel];
                    oacc[g][nt] = MFMA16(ap, bv, oacc[g][nt]);
                }
            }
        }

        // ---- commit prefetched tile ----
        if (kt < 15) {
            const int nxt = cur ^ 1;
            #pragma unroll
            for (int i = 0; i < 2; ++i) {
                int ch = tid + 256 * i;
                int r = ch >> 3, cc = ch & 7;
                *(short8*)&Klds[nxt][r * 64 + ((cc ^ (r & 7)) * 8)] = kpre[i];
                *(short8*)&Vlds[nxt][r * 64 + ((cc ^ (r & 7)) * 8)] = vpre[i];
            }
        }
        __syncthreads();   // single barrier per kt
    }

    // ---- deferred denominator: one 16-lane reduce per (g, r) ----
    float inv[2][4];
    #pragma unroll
    for (int g = 0; g < 2; ++g)
        #pragma unroll
        for (int r = 0; r < 4; ++r) {
            float s = lrun[g][r];
            #pragma unroll
            for (int off = 1; off < 16; off <<= 1)
                s += __shfl_xor(s, off, 16);
            inv[g][r] = __builtin_amdgcn_rcpf(s);
        }

    // ---- fused output projection: out_tile = (O/l) * Wo[h] ----
    const int b  = bh >> 4, hh = bh & 15;
    {
        const float* wo = Wo + (size_t)hh * D_ * D_;
        #pragma unroll
        for (int i = 0; i < 2; ++i) {
            int ch = tid + 256 * i;          // e = ch>>3, dc = ch&7
            int e = ch >> 3, dc = ch & 7;
            short8 vch;
            #pragma unroll
            for (int j = 0; j < 8; ++j)
                vch[j] = (short)f2h(wo[(size_t)(dc * 8 + j) * D_ + e]);
            *(short8*)&Klds[0][e * 64 + ((dc ^ (e & 7)) * 8)] = vch;
        }
    }
    // O relayout + A-fragment reads, serialized over g (wave-local Pw reuse)
    f16x8 ao[2][2];
    {
        u16* Pw = Plds[w];
        #pragma unroll
        for (int g = 0; g < 2; ++g) {
            #pragma unroll
            for (int nt = 0; nt < 4; ++nt) {
                int col = 16 * nt + l15;             // d
                #pragma unroll
                for (int r = 0; r < 4; ++r) {
                    int row = quad * 4 + r;          // q
                    Pw[row * 64 + (((col >> 3) ^ (row & 7)) * 8) + (col & 7)] =
                        f2h(oacc[g][nt][r] * inv[g][r]);
                }
            }
            ao[g][0] = *(const f16x8*)&Pw[l15 * 64 + (((quad + 0) ^ sw) * 8)];
            ao[g][1] = *(const f16x8*)&Pw[l15 * 64 + (((quad + 4) ^ sw) * 8)];
        }
    }
    __syncthreads();    // Wo^T staging visible to all waves

    f32x4 oo[2][4];
    #pragma unroll
    for (int g = 0; g < 2; ++g)
        #pragma unroll
        for (int nt = 0; nt < 4; ++nt)
            oo[g][nt] = (f32x4){0.f, 0.f, 0.f, 0.f};
    #pragma unroll
    for (int nt = 0; nt < 4; ++nt) {
        int erow = 16 * nt + l15;
        f16x8 b0 = *(const f16x8*)&Klds[0][erow * 64 + (((quad + 0) ^ (erow & 7)) * 8)];
        f16x8 b1 = *(const f16x8*)&Klds[0][erow * 64 + (((quad + 4) ^ (erow & 7)) * 8)];
        #pragma unroll
        for (int g = 0; g < 2; ++g) {
            oo[g][nt] = MFMA16(ao[g][0], b0, oo[g][nt]);
            oo[g][nt] = MFMA16(ao[g][1], b1, oo[g][nt]);
        }
    }
    #pragma unroll
    for (int g = 0; g < 2; ++g)
        #pragma unroll
        for (int nt = 0; nt < 4; ++nt)
            #pragma unroll
            for (int r = 0; r < 4; ++r) {
                int qg = qt * 128 + (w + 4 * g) * 16 + quad * 4 + r;
                int e  = 16 * nt + l15;
                out[((size_t)b * T_ + qg) * E_ + hh * D_ + e] = oo[g][nt][r];
            }
}

// ---------------------------------------------------------------------------
extern "C" void kernel_launch(void* const* d_in, const int* in_sizes, int n_in,
                              void* d_out, int out_size, void* d_ws, size_t ws_size,
                              hipStream_t stream)
{
    const float* src = (const float*)d_in[0];
    const float* tgt = (const float*)d_in[1];
    const float* Wq  = (const float*)d_in[2];
    const float* Wv  = (const float*)d_in[3];
    const float* Wo  = (const float*)d_in[4];
    const float* Wih = (const float*)d_in[5];
    const float* Whh = (const float*)d_in[6];
    const float* bih = (const float*)d_in[7];
    const float* bhh = (const float*)d_in[8];
    float* out = (float*)d_out;

    char* ws = (char*)d_ws;
    u16* qh  = (u16*)(ws);                             // [bh][t][d] 16 MB
    u16* vh  = (u16*)(ws + (size_t)16 * 1024 * 1024);  // V^T [bh][d][t] 16 MB
    u16* nwh = (u16*)(ws + (size_t)32 * 1024 * 1024);  // [bh][t][d] 16 MB

    (void)in_sizes; (void)n_in; (void)out_size; (void)ws_size;

    proj_rnn_kernel<<<dim3(BH_ + 4096), 256, 0, stream>>>(
        src, tgt, Wq, Wv, Wih, Whh, bih, bhh, qh, vh, nwh);
    // bh on the FAST grid axis: all 8 qt-blocks of a bh share an XCD (L2 reuse)
    attn_kernel<<<dim3(BH_, 8), 256, 0, stream>>>(qh, nwh, vh, Wo, out);
}